// Round 6
// baseline (21.934 us; speedup 1.0000x reference)
//
#include <hip/hip_runtime.h>

// WeightedBoxPool, single kernel, no LDS staging, no atomics, no workspace.
//   out[b,j] = sum_t mask_weight[b,t,j] * [ max_{i beats j} fl(iou(i,j)) < thr[t] ]
//   beat = score_i>score_j || (score_i==score_j && i<j)
//        <=> key_i > key_j, key = (score_bits<<32) | (0x7fffffff - idx)  (scores > 0)
// Block = 256 threads owning JG=8 consecutive j's; each thread scans i = i0+tid
// (stride 256, coalesced) with an A/B software-pipelined record prefetch, and
// keeps JG division-free running maxes (nb,db) via cross-multiply compare.
// One IEEE f32 divide per (lane,j), shfl_xor wave max-reduce, LDS cross-wave
// reduce. Rounding is monotone, so max of correctly-rounded chunk quotients
// >= t iff some per-i quotient >= t — bit-identical to the reference compares
// (absmax 0.0 in rounds 2-5 with this exact arithmetic).

constexpr int JG   = 8;            // j columns per block
constexpr int NW   = 4;            // waves per block
constexpr int NTHR = NW * 64;      // 256

__global__ __launch_bounds__(NTHR)
void wbp_kernel(const float* __restrict__ box,    // [B,4,N]
                const float* __restrict__ score,  // [B,1,N]
                const float* __restrict__ mw,     // [B,T,N]
                const float* __restrict__ thr,    // [T]
                float* __restrict__ out,          // [B,1,N]
                int N, int T)
{
    const int b     = blockIdx.y;
    const int jbase = blockIdx.x * JG;
    const int tid   = threadIdx.x;
    const int lane  = tid & 63;
    const int wave  = tid >> 6;

    const float* __restrict__ bx1 = box + (size_t)(b * 4 + 0) * N;
    const float* __restrict__ by1 = box + (size_t)(b * 4 + 1) * N;
    const float* __restrict__ bx2 = box + (size_t)(b * 4 + 2) * N;
    const float* __restrict__ by2 = box + (size_t)(b * 4 + 3) * N;
    const float* __restrict__ sc  = score + (size_t)b * N;

    // j-state in registers (block-uniform addresses -> scalar loads)
    float jx1[JG], jy1[JG], jx2[JG], jy2[JG], ja[JG];
    unsigned long long jkey[JG];
    #pragma unroll
    for (int u = 0; u < JG; ++u) {
        const int j  = jbase + u;
        const int jc = min(j, N - 1);
        jx1[u] = bx1[jc]; jy1[u] = by1[jc]; jx2[u] = bx2[jc]; jy2[u] = by2[jc];
        ja[u]  = (jx2[u] - jx1[u]) * (jy2[u] - jy1[u]);
        jkey[u] = (j < N)
            ? (((unsigned long long)__float_as_uint(sc[jc]) << 32)
               | (unsigned int)(0x7fffffff - j))
            : ~0ull;                              // j OOB: unbeatable -> q stays 0
    }

    float nb[JG], db[JG];                         // running max quotient nb/db per j
    #pragma unroll
    for (int u = 0; u < JG; ++u) { nb[u] = 0.f; db[u] = 1.f; }

    const int D = (N + NTHR - 1) / NTHR;          // i-chunks per thread

    // A/B software-pipelined i-record registers (compile-time named, no arrays)
    float ax1, ay1, ax2, ay2, as_;
    float cx1, cy1, cx2, cy2, cs_;

    auto LOADA = [&](int d) {
        const int ic = min(d * NTHR + tid, N - 1);
        ax1 = bx1[ic]; ay1 = by1[ic]; ax2 = bx2[ic]; ay2 = by2[ic]; as_ = sc[ic];
    };
    auto LOADB = [&](int d) {
        const int ic = min(d * NTHR + tid, N - 1);
        cx1 = bx1[ic]; cy1 = by1[ic]; cx2 = bx2[ic]; cy2 = by2[ic]; cs_ = sc[ic];
    };
    auto EVAL = [&](int d, float ix1, float iy1, float ix2, float iy2, float is) {
        const int i = d * NTHR + tid;
        const unsigned long long ikey = (i < N)
            ? (((unsigned long long)__float_as_uint(is) << 32)
               | (unsigned int)(0x7fffffff - i))
            : 0ull;                               // OOB: key 0 never beats
        const float ia = (ix2 - ix1) * (iy2 - iy1);   // same expr as reference area
        #pragma unroll
        for (int u = 0; u < JG; ++u) {
            const float ltx = fmaxf(jx1[u], ix1);
            const float lty = fmaxf(jy1[u], iy1);
            const float rbx = fminf(jx2[u], ix2);
            const float rby = fminf(jy2[u], iy2);
            const float w   = fmaxf(rbx - ltx, 0.f);
            const float h   = fmaxf(rby - lty, 0.f);
            const float inter = w * h;
            const float uni   = (ja[u] + ia) - inter;
            const bool take = (ikey > jkey[u]) && (inter * db[u] > nb[u] * uni);
            if (take) { nb[u] = inter; db[u] = uni; }   // branchless cndmask pair
        }
    };

    // ping-pong pipeline: loads for step d+1 issued before evaluating step d
    int d = 0;
    LOADA(0);
    for (; d + 2 <= D; d += 2) {
        LOADB(d + 1);
        EVAL(d, ax1, ay1, ax2, ay2, as_);
        if (d + 2 < D) LOADA(d + 2);
        EVAL(d + 1, cx1, cy1, cx2, cy2, cs_);
    }
    if (d < D) EVAL(d, ax1, ay1, ax2, ay2, as_);

    // one IEEE divide per (lane, j); wave-level max reduce via shuffles
    __shared__ float pq[NW][JG];
    float qr[JG];
    #pragma unroll
    for (int u = 0; u < JG; ++u) {
        float q = (nb[u] > 0.f) ? (nb[u] / db[u]) : 0.f;
        #pragma unroll
        for (int m = 32; m >= 1; m >>= 1)
            q = fmaxf(q, __shfl_xor(q, m, 64));
        qr[u] = q;
    }
    if (lane == 0) {
        #pragma unroll
        for (int u = 0; u < JG; ++u) pq[wave][u] = qr[u];
    }
    __syncthreads();

    if (tid < JG) {
        const int j = jbase + tid;
        if (j < N) {
            const float qm = fmaxf(fmaxf(pq[0][tid], pq[1][tid]),
                                   fmaxf(pq[2][tid], pq[3][tid]));
            float acc = 0.f;
            for (int t = 0; t < T; ++t)
                if (qm < thr[t])                  // survived threshold t
                    acc += mw[(size_t)(b * T + t) * N + j];
            out[(size_t)b * N + j] = acc;
        }
    }
}

extern "C" void kernel_launch(void* const* d_in, const int* in_sizes, int n_in,
                              void* d_out, int out_size, void* d_ws, size_t ws_size,
                              hipStream_t stream)
{
    const float* mw  = (const float*)d_in[0];   // [B,T,N]
    const float* box = (const float*)d_in[1];   // [B,4,N]
    const float* sc  = (const float*)d_in[2];   // [B,1,N]
    const float* thr = (const float*)d_in[3];   // [T]
    float* out = (float*)d_out;                 // [B,1,N]

    const int BN = in_sizes[2];
    const int T  = in_sizes[3];
    const int B  = 4;                           // problem constant
    const int N  = BN / B;

    dim3 grid((N + JG - 1) / JG, B);
    wbp_kernel<<<grid, NTHR, 0, stream>>>(box, sc, mw, thr, out, N, T);
}